// Round 5
// baseline (1628.631 us; speedup 1.0000x reference)
//
#include <hip/hip_runtime.h>

// ---------------------------------------------------------------------------
// Round 9: MFMA for the two dense GEMMs (kv-projection + output projection)
// via fp32 -> bf16 hi/lo split (3 MFMAs per tile: Ah*Bh + Ah*Bl + Al*Bh).
// Softmax/QK^T/PV keep the proven round-8 fp32 structure.
//   - Weights pre-transposed + split into bf16 hi/lo tables in d_ws (3 MB)
//     by a prep kernel; hot loops load 16-B short8 fragments.
//   - Activations stay fp32 in LDS ([49][36] padded, 2-way = free),
//     converted in-register per K-step (RNE hi, RNE lo of remainder).
//   - Host falls back to the round-8 fp32 kernels if ws_size < 3 MB.
// MFMA mapping (m89/m91-verified): A: row=l&15, k=(l>>4)*8+e;
// B: col=l&15, same k; D: col=l&15, row=(l>>4)*4+r.
// ---------------------------------------------------------------------------

typedef unsigned int  u32;
typedef unsigned short u16;
typedef __attribute__((ext_vector_type(8))) short bf16x8;
typedef __attribute__((ext_vector_type(4))) float f32x4;

// ws layout (u16 elements):
//   [0)        qkvT_hi [1024][512]
//   [524288)   qkvT_lo [1024][512]
//   [1048576)  projT_hi [512][512]
//   [1310720)  projT_lo [512][512]   -> total 1572864 u16 = 3 MiB

// RNE f32 -> bf16 hi, then RNE bf16 of remainder.
#define CVT1(x, he, le) {                                                      \
    u32 _u = __float_as_uint(x);                                               \
    u32 _hb = (_u + 0x7FFFu + ((_u >> 16) & 1u)) >> 16;                        \
    float _hf = __uint_as_float(_hb << 16);                                    \
    float _lf = (x) - _hf;                                                     \
    u32 _ul = __float_as_uint(_lf);                                            \
    he = (short)(u16)_hb;                                                      \
    le = (short)(u16)((_ul + 0x7FFFu + ((_ul >> 16) & 1u)) >> 16); }

__device__ __forceinline__ void cvt8(const float4 a0, const float4 a1,
                                     bf16x8& h, bf16x8& l) {
    CVT1(a0.x, h[0], l[0])  CVT1(a0.y, h[1], l[1])
    CVT1(a0.z, h[2], l[2])  CVT1(a0.w, h[3], l[3])
    CVT1(a1.x, h[4], l[4])  CVT1(a1.y, h[5], l[5])
    CVT1(a1.z, h[6], l[6])  CVT1(a1.w, h[7], l[7])
}

// ---- prep: transpose + split weights into bf16 hi/lo tables ---------------
__global__ __launch_bounds__(256) void prep_wt(const float* __restrict__ qkv_w,
                                               const float* __restrict__ proj_w,
                                               u16* __restrict__ ws) {
    const int tid = blockIdx.x * 256 + threadIdx.x;   // 0 .. 786431
    if (tid < 524288) {                               // qkv_w [512][1024]
        const int n = tid >> 9, k = tid & 511;
        const float x = qkv_w[(size_t)k * 1024 + n];
        short h, l; CVT1(x, h, l)
        ws[tid] = (u16)h; ws[524288 + tid] = (u16)l;  // qkvT[n*512+k]
    } else {                                          // proj_w [512][512]
        const int f = tid - 524288;
        const int n = f >> 9, k = f & 511;
        const float x = proj_w[(size_t)k * 512 + n];
        short h, l; CVT1(x, h, l)
        ws[1048576 + f] = (u16)h; ws[1310720 + f] = (u16)l;
    }
}

// ---------------------------------------------------------------------------
// attn2_mfma: block = (window, head-pair). Phase 1 (kv tile 49x128) on MFMA;
// phases 2-4 are round-8 fp32 (wave softmax, PV).
// ---------------------------------------------------------------------------
__global__ __launch_bounds__(256, 3) void attn2_mfma(
    const float* __restrict__ inp, const float* __restrict__ qg,
    const u16* __restrict__ wt, const float* __restrict__ b,
    const float* __restrict__ bt, float* __restrict__ out) {
    __shared__ float kv_s[49][132];     // 25872 B; c<64 k, c>=64 v
    __shared__ float S_s[49][50];       //  9800 B
    __shared__ float inp_s[2][49][36];  // 14112 B; padded: A-frag reads 2-way
    // total 49784 B -> 3 blocks/CU

    const int win = blockIdx.x;
    const int hg  = blockIdx.y;          // head pair 0..7
    const int t   = threadIdx.x;
    const int wv  = t >> 6;              // wave id 0..3 (M-tile id)
    const int l   = t & 63;              // lane
    const int lr  = l & 15;              // row-in-tile / col-in-tile
    const int lk  = l >> 4;              // k-group 0..3
    const int lk8 = lk << 3;

    const float* ip = inp + (size_t)win * 49 * 512;

    // staging indices: 392 float4 per 49x32 chunk
    const int o1 = t + 256;
    const bool has2 = (o1 < 392);
    const int sr0 = t >> 3,  sc0 = (t & 7) << 2;
    const int sr1 = o1 >> 3, sc1 = (o1 & 7) << 2;

    const int arow = min(16 * wv + lr, 48);   // clamp: wave-3 pad rows

    const u16* wt_hi = wt;
    const u16* wt_lo = wt + 524288;
    const size_t rowK = (size_t)(hg * 64 + lr) * 512 + lk8;        // k cols
    const size_t rowV = (size_t)(512 + hg * 64 + lr) * 512 + lk8;  // v cols

    f32x4 acc[8];
#pragma unroll
    for (int n = 0; n < 8; ++n) acc[n] = (f32x4){0.f, 0.f, 0.f, 0.f};

    // prologue: stage chunk 0
    {
        float4 s0 = *(const float4*)(ip + (size_t)sr0 * 512 + sc0);
        float4 s1;
        if (has2) s1 = *(const float4*)(ip + (size_t)sr1 * 512 + sc1);
        *(float4*)&inp_s[0][sr0][sc0] = s0;
        if (has2) *(float4*)&inp_s[0][sr1][sc1] = s1;
    }
    __syncthreads();

    for (int ks = 0; ks < 16; ++ks) {
        const int cur = ks & 1;
        float4 st0, st1;
        if (ks < 15) {   // issue next-chunk loads first (latency hidden)
            const float* src = ip + ((ks + 1) << 5);
            st0 = *(const float4*)(src + (size_t)sr0 * 512 + sc0);
            if (has2) st1 = *(const float4*)(src + (size_t)sr1 * 512 + sc1);
        }
        // A fragment (fp32 from LDS -> hi/lo bf16)
        float4 a0 = *(const float4*)&inp_s[cur][arow][lk8];
        float4 a1 = *(const float4*)&inp_s[cur][arow][lk8 + 4];
        bf16x8 ah, al; cvt8(a0, a1, ah, al);

        const u16* pkh = wt_hi + rowK + (ks << 5);
        const u16* pkl = wt_lo + rowK + (ks << 5);
        const u16* pvh = wt_hi + rowV + (ks << 5);
        const u16* pvl = wt_lo + rowV + (ks << 5);

        bf16x8 Bh[8], Bl[8];
#pragma unroll
        for (int n = 0; n < 4; ++n) {      // nt stride = 16 rows * 512 = 8192
            Bh[n]     = *(const bf16x8*)(pkh + ((size_t)n << 13));
            Bh[4 + n] = *(const bf16x8*)(pvh + ((size_t)n << 13));
        }
#pragma unroll
        for (int n = 0; n < 4; ++n) {
            Bl[n]     = *(const bf16x8*)(pkl + ((size_t)n << 13));
            Bl[4 + n] = *(const bf16x8*)(pvl + ((size_t)n << 13));
        }
#pragma unroll
        for (int n = 0; n < 8; ++n)
            acc[n] = __builtin_amdgcn_mfma_f32_16x16x32_bf16(ah, Bh[n], acc[n], 0, 0, 0);
#pragma unroll
        for (int n = 0; n < 8; ++n)
            acc[n] = __builtin_amdgcn_mfma_f32_16x16x32_bf16(ah, Bl[n], acc[n], 0, 0, 0);
#pragma unroll
        for (int n = 0; n < 8; ++n)
            acc[n] = __builtin_amdgcn_mfma_f32_16x16x32_bf16(al, Bh[n], acc[n], 0, 0, 0);

        if (ks < 15) {   // write next chunk after compute
            *(float4*)&inp_s[cur ^ 1][sr0][sc0] = st0;
            if (has2) *(float4*)&inp_s[cur ^ 1][sr1][sc1] = st1;
        }
        __syncthreads();
    }

    // writeback kv tile (+bias); D: row=(l>>4)*4+r (+16*wv), col=nt*16+lr
#pragma unroll
    for (int n = 0; n < 8; ++n) {
        const int colg = (n < 4) ? (hg * 64 + n * 16 + lr)
                                 : (512 + hg * 64 + (n - 4) * 16 + lr);
        const float bias = b[colg];
        const int cloc = n * 16 + lr;
#pragma unroll
        for (int r = 0; r < 4; ++r) {
            const int row = 16 * wv + 4 * lk + r;
            if (row < 49) kv_s[row][cloc] = acc[n][r] + bias;
        }
    }

    // stage BOTH q head slices (buf0 = head0, buf1 = head1)
    const float* qwin = qg + (size_t)(win >> 4) * 49 * 512 + (hg << 6);
    {
        float4 q00 = *(const float4*)(qwin + (size_t)sr0 * 512 + sc0);
        float4 q10 = *(const float4*)(qwin + 32 + (size_t)sr0 * 512 + sc0);
        float4 q01, q11;
        if (has2) {
            q01 = *(const float4*)(qwin + (size_t)sr1 * 512 + sc1);
            q11 = *(const float4*)(qwin + 32 + (size_t)sr1 * 512 + sc1);
        }
        *(float4*)&inp_s[0][sr0][sc0] = q00;
        *(float4*)&inp_s[1][sr0][sc0] = q10;
        if (has2) {
            *(float4*)&inp_s[0][sr1][sc1] = q01;
            *(float4*)&inp_s[1][sr1][sc1] = q11;
        }
    }
    __syncthreads();

    // ---- phases 2-4 per head (round-8 proven structure) ------------------
    const int j  = l;
    const int jj = (j < 49) ? j : 48;
    const int jh = jj / 7, jw = jj - jh * 7;
    const int c_j = jh * 13 + jw;

    for (int hh = 0; hh < 2; ++hh) {
        const int H = (hg << 1) + hh;

        float4 kreg[8];
#pragma unroll
        for (int d4 = 0; d4 < 8; ++d4)
            kreg[d4] = *(const float4*)&kv_s[jj][(hh << 5) + (d4 << 2)];

        for (int i = wv; i < 49; i += 4) {
            const int ih = i / 7, iw = i - ih * 7;
            const int r_i = ih * 13 + iw + 84;
            float s = 0.f;
#pragma unroll
            for (int d4 = 0; d4 < 8; ++d4) {
                float4 qv = *(const float4*)&inp_s[hh][i][d4 << 2];  // broadcast
                s = fmaf(qv.x, kreg[d4].x, s); s = fmaf(qv.y, kreg[d4].y, s);
                s = fmaf(qv.z, kreg[d4].z, s); s = fmaf(qv.w, kreg[d4].w, s);
            }
            s = s * 0.17677669529663687f + bt[(r_i - c_j) * 16 + H];
            if (j >= 49) s = -1e30f;
            float mx = s;
#pragma unroll
            for (int m = 32; m; m >>= 1) mx = fmaxf(mx, __shfl_xor(mx, m));
            float e = __expf(s - mx);
            float sum = e;
#pragma unroll
            for (int m = 32; m; m >>= 1) sum += __shfl_xor(sum, m);
            float p = e * (1.f / sum);
            if (j < 49) S_s[i][j] = p;
        }
        __syncthreads();

        for (int o = t; o < 392; o += 256) {
            int i = o >> 3, dd = (o & 7) << 2;
            float4 a4 = make_float4(0.f, 0.f, 0.f, 0.f);
#pragma unroll 7
            for (int jq = 0; jq < 49; ++jq) {
                float p = S_s[i][jq];
                float4 vf = *(const float4*)&kv_s[jq][64 + (hh << 5) + dd];
                a4.x = fmaf(p, vf.x, a4.x); a4.y = fmaf(p, vf.y, a4.y);
                a4.z = fmaf(p, vf.z, a4.z); a4.w = fmaf(p, vf.w, a4.w);
            }
            *(float4*)(out + ((size_t)win * 49 + i) * 512 + (H << 5) + dd) = a4;
        }
        __syncthreads();
    }
}

// ---------------------------------------------------------------------------
// proj_mfma: 16 rows/block; wave wv owns cols wv*128..wv*128+127 (8 N-tiles).
// Same hi/lo-split MFMA; in-place (block owns its rows; stores after reads).
// ---------------------------------------------------------------------------
__global__ __launch_bounds__(256, 3) void proj_mfma(
    const u16* __restrict__ wt, const float* __restrict__ pb,
    float* __restrict__ io) {
    __shared__ float X_s[2][16][36];   // 4608 B
    const int m0 = blockIdx.x << 4;
    const int t  = threadIdx.x;
    const int wv = t >> 6, l = t & 63, lr = l & 15, lk = l >> 4;
    const int lk8 = lk << 3;
    const int ncol = wv << 7;          // wave's col base

    const float* xp = io + (size_t)m0 * 512;
    const int sr = t >> 3, sc = (t & 7) << 2;   // t<128 stages 128 f4
    const bool st_on = (t < 128);

    const u16* p_hi = wt + 1048576 + (size_t)(ncol + lr) * 512 + lk8;
    const u16* p_lo = wt + 1310720 + (size_t)(ncol + lr) * 512 + lk8;
    const int arow = lr;

    f32x4 acc[8];
#pragma unroll
    for (int n = 0; n < 8; ++n) acc[n] = (f32x4){0.f, 0.f, 0.f, 0.f};

    if (st_on)
        *(float4*)&X_s[0][sr][sc] = *(const float4*)(xp + (size_t)sr * 512 + sc);
    __syncthreads();

    for (int ks = 0; ks < 16; ++ks) {
        const int cur = ks & 1;
        float4 st;
        if (ks < 15 && st_on)
            st = *(const float4*)(xp + ((ks + 1) << 5) + (size_t)sr * 512 + sc);

        float4 a0 = *(const float4*)&X_s[cur][arow][lk8];
        float4 a1 = *(const float4*)&X_s[cur][arow][lk8 + 4];
        bf16x8 ah, al; cvt8(a0, a1, ah, al);

        const u16* ph = p_hi + (ks << 5);
        const u16* pl = p_lo + (ks << 5);
        bf16x8 Bh[8], Bl[8];
#pragma unroll
        for (int n = 0; n < 8; ++n) Bh[n] = *(const bf16x8*)(ph + ((size_t)n << 13));
#pragma unroll
        for (int n = 0; n < 8; ++n) Bl[n] = *(const bf16x8*)(pl + ((size_t)n << 13));
#pragma unroll
        for (int n = 0; n < 8; ++n)
            acc[n] = __builtin_amdgcn_mfma_f32_16x16x32_bf16(ah, Bh[n], acc[n], 0, 0, 0);
#pragma unroll
        for (int n = 0; n < 8; ++n)
            acc[n] = __builtin_amdgcn_mfma_f32_16x16x32_bf16(ah, Bl[n], acc[n], 0, 0, 0);
#pragma unroll
        for (int n = 0; n < 8; ++n)
            acc[n] = __builtin_amdgcn_mfma_f32_16x16x32_bf16(al, Bh[n], acc[n], 0, 0, 0);

        if (ks < 15 && st_on)
            *(float4*)&X_s[cur ^ 1][sr][sc] = st;
        __syncthreads();
    }

    // epilogue: D row = 4*lk + r, col = ncol + nt*16 + lr
#pragma unroll
    for (int n = 0; n < 8; ++n) {
        const int col = ncol + n * 16 + lr;
        const float bias = pb[col];
#pragma unroll
        for (int r = 0; r < 4; ++r)
            io[(size_t)(m0 + 4 * lk + r) * 512 + col] = acc[n][r] + bias;
    }
}

// ===========================================================================
// fp32 fallback path (round-8 kernels, verbatim) — used if ws_size < 3 MiB.
// ===========================================================================
typedef __attribute__((address_space(3))) void lds_void;
typedef const __attribute__((address_space(1))) void glb_void;

__device__ __forceinline__ void cp16_async(const float* g, float* lds_wave_base) {
    __builtin_amdgcn_global_load_lds((glb_void*)g, (lds_void*)lds_wave_base, 16, 0, 0);
}

__device__ __forceinline__ void stage49x32(const float* src, float* dst, int t) {
#pragma unroll
    for (int it = 0; it < 2; ++it) {
        const int o = t + (it << 8);
        if (o < 392) {
            const int wb = o & ~63;
            cp16_async(src + (size_t)(o >> 3) * 512 + ((o & 7) << 2),
                       dst + (wb << 2));
        }
    }
}

#define FMA4(accv, f, w0, w1, w2, w3)                                          \
  accv.x = fmaf(f.x, w0.x, accv.x); accv.x = fmaf(f.y, w1.x, accv.x);          \
  accv.x = fmaf(f.z, w2.x, accv.x); accv.x = fmaf(f.w, w3.x, accv.x);          \
  accv.y = fmaf(f.x, w0.y, accv.y); accv.y = fmaf(f.y, w1.y, accv.y);          \
  accv.y = fmaf(f.z, w2.y, accv.y); accv.y = fmaf(f.w, w3.y, accv.y);          \
  accv.z = fmaf(f.x, w0.z, accv.z); accv.z = fmaf(f.y, w1.z, accv.z);          \
  accv.z = fmaf(f.z, w2.z, accv.z); accv.z = fmaf(f.w, w3.z, accv.z);          \
  accv.w = fmaf(f.x, w0.w, accv.w); accv.w = fmaf(f.y, w1.w, accv.w);          \
  accv.w = fmaf(f.z, w2.w, accv.w); accv.w = fmaf(f.w, w3.w, accv.w);

__global__ __launch_bounds__(256, 3) void attn2_fp32(
    const float* __restrict__ inp, const float* __restrict__ qg,
    const float* __restrict__ W, const float* __restrict__ b,
    const float* __restrict__ bt, float* __restrict__ out) {
    __shared__ float kv_s[56][132];
    __shared__ float S_s[49][50];
    __shared__ float inp_s[2][56][32];
    const int win = blockIdx.x, hg = blockIdx.y, t = threadIdx.x;
    const int c4 = t & 31, rg = t >> 5, wv = t >> 6, j = t & 63;
    const int colbase = (c4 < 16) ? (hg * 64 + (c4 << 2))
                                  : (512 + hg * 64 + ((c4 - 16) << 2));
    const float* ip = inp + (size_t)win * 49 * 512;
    float4 acc[7];
#pragma unroll
    for (int rr = 0; rr < 7; ++rr) acc[rr] = make_float4(0.f, 0.f, 0.f, 0.f);
    const float4 bias4 = *(const float4*)(b + colbase);
    stage49x32(ip, &inp_s[0][0][0], t);
    __syncthreads();
    for (int kc = 0; kc < 512; kc += 32) {
        const int cur = (kc >> 5) & 1;
        if (kc + 32 < 512) stage49x32(ip + kc + 32, &inp_s[cur ^ 1][0][0], t);
        const float* Wp = W + ((size_t)kc << 10) + colbase;
#pragma unroll
        for (int k4 = 0; k4 < 8; ++k4) {
            const float* wr = Wp + ((size_t)(k4 << 2) << 10);
            float4 w0 = *(const float4*)(wr);
            float4 w1 = *(const float4*)(wr + 1024);
            float4 w2 = *(const float4*)(wr + 2048);
            float4 w3 = *(const float4*)(wr + 3072);
#pragma unroll
            for (int rr = 0; rr < 7; ++rr) {
                float4 f = *(const float4*)&inp_s[cur][rg + (rr << 3)][k4 << 2];
                FMA4(acc[rr], f, w0, w1, w2, w3)
            }
        }
        __syncthreads();
    }
#pragma unroll
    for (int rr = 0; rr < 7; ++rr) {
        const int r = rg + (rr << 3);
        float4 res = make_float4(acc[rr].x + bias4.x, acc[rr].y + bias4.y,
                                 acc[rr].z + bias4.z, acc[rr].w + bias4.w);
        *(float4*)&kv_s[r][c4 << 2] = res;
    }
    const float* qwin = qg + (size_t)(win >> 4) * 49 * 512 + (hg << 6);
    stage49x32(qwin, &inp_s[0][0][0], t);
    __syncthreads();
    const int jj = (j < 49) ? j : 48;
    const int jh = jj / 7, jw = jj - jh * 7;
    const int c_j = jh * 13 + jw;
    for (int hh = 0; hh < 2; ++hh) {
        const int H = (hg << 1) + hh;
        const int qb = hh;
        if (hh == 0) stage49x32(qwin + 32, &inp_s[1][0][0], t);
        float4 kreg[8];
#pragma unroll
        for (int d4 = 0; d4 < 8; ++d4)
            kreg[d4] = *(const float4*)&kv_s[jj][(hh << 5) + (d4 << 2)];
        for (int i = wv; i < 49; i += 4) {
            const int ih = i / 7, iw = i - ih * 7;
            const int r_i = ih * 13 + iw + 84;
            float s = 0.f;
#pragma unroll
            for (int d4 = 0; d4 < 8; ++d4) {
                float4 qv = *(const float4*)&inp_s[qb][i][d4 << 2];
                s = fmaf(qv.x, kreg[d4].x, s); s = fmaf(qv.y, kreg[d4].y, s);
                s = fmaf(qv.z, kreg[d4].z, s); s = fmaf(qv.w, kreg[d4].w, s);
            }
            s = s * 0.17677669529663687f + bt[(r_i - c_j) * 16 + H];
            if (j >= 49) s = -1e30f;
            float mx = s;
#pragma unroll
            for (int m = 32; m; m >>= 1) mx = fmaxf(mx, __shfl_xor(mx, m));
            float e = __expf(s - mx);
            float sum = e;
#pragma unroll
            for (int m = 32; m; m >>= 1) sum += __shfl_xor(sum, m);
            float p = e * (1.f / sum);
            if (j < 49) S_s[i][j] = p;
        }
        __syncthreads();
        for (int o = t; o < 392; o += 256) {
            int i = o >> 3, dd = (o & 7) << 2;
            float4 a4 = make_float4(0.f, 0.f, 0.f, 0.f);
#pragma unroll 7
            for (int jq = 0; jq < 49; ++jq) {
                float p = S_s[i][jq];
                float4 vf = *(const float4*)&kv_s[jq][64 + (hh << 5) + dd];
                a4.x = fmaf(p, vf.x, a4.x); a4.y = fmaf(p, vf.y, a4.y);
                a4.z = fmaf(p, vf.z, a4.z); a4.w = fmaf(p, vf.w, a4.w);
            }
            *(float4*)(out + ((size_t)win * 49 + i) * 512 + (H << 5) + dd) = a4;
        }
        __syncthreads();
    }
}

__global__ __launch_bounds__(256, 4) void proj16_fp32(
    const float* __restrict__ pw, const float* __restrict__ pb,
    float* __restrict__ io) {
    __shared__ float X_s[16][512];
    const int m0 = blockIdx.x << 4;
    const int t = threadIdx.x;
    const int c4 = (t & 127) << 2;
    const int rg = t >> 7;
    const float* xsrc = io + (size_t)m0 * 512;
#pragma unroll
    for (int it = 0; it < 8; ++it) {
        const int o = t + (it << 8);
        const int wb = o & ~63;
        cp16_async(xsrc + ((size_t)o << 2), &X_s[0][0] + (wb << 2));
    }
    __syncthreads();
    const float4 bias = *(const float4*)(pb + c4);
    float4 acc[8];
#pragma unroll
    for (int r = 0; r < 8; ++r) acc[r] = bias;
    const float* wp = pw + c4;
    float4 w0 = *(const float4*)(wp);
    float4 w1 = *(const float4*)(wp + 512);
    float4 w2 = *(const float4*)(wp + 1024);
    float4 w3 = *(const float4*)(wp + 1536);
    for (int k4 = 0; k4 < 127; ++k4) {
        const float* wn = wp + (((size_t)k4 + 1) << 11);
        const float4 n0 = *(const float4*)(wn);
        const float4 n1 = *(const float4*)(wn + 512);
        const float4 n2 = *(const float4*)(wn + 1024);
        const float4 n3 = *(const float4*)(wn + 1536);
#pragma unroll
        for (int r = 0; r < 8; ++r) {
            const float4 f = *(const float4*)&X_s[(rg << 3) + r][k4 << 2];
            FMA4(acc[r], f, w0, w1, w2, w3)
        }
        w0 = n0; w1 = n1; w2 = n2; w3 = n3;
    }
#pragma unroll
    for (int r = 0; r < 8; ++r) {
        const float4 f = *(const float4*)&X_s[(rg << 3) + r][127 << 2];
        FMA4(acc[r], f, w0, w1, w2, w3)
    }
#pragma unroll
    for (int r = 0; r < 8; ++r)
        *(float4*)(io + ((size_t)(m0 + (rg << 3) + r)) * 512 + c4) = acc[r];
}

// ---------------------------------------------------------------------------
extern "C" void kernel_launch(void* const* d_in, const int* in_sizes, int n_in,
                              void* d_out, int out_size, void* d_ws, size_t ws_size,
                              hipStream_t stream) {
    const float* inputs = (const float*)d_in[0];   // [1024*49, 512]
    const float* qg     = (const float*)d_in[1];   // [64*49, 512]
    const float* qkv_w  = (const float*)d_in[2];   // [512, 1024]
    const float* qkv_b  = (const float*)d_in[3];   // [1024]
    const float* btab   = (const float*)d_in[4];   // [169, 16]
    const float* proj_w = (const float*)d_in[5];   // [512, 512]
    const float* proj_b = (const float*)d_in[6];   // [512]
    float* out = (float*)d_out;                    // [1024*49, 512]

    const size_t WS_NEED = 1572864ull * sizeof(unsigned short);  // 3 MiB
    if (d_ws != nullptr && ws_size >= WS_NEED) {
        unsigned short* wt = (unsigned short*)d_ws;
        prep_wt<<<3072, 256, 0, stream>>>(qkv_w, proj_w, wt);
        attn2_mfma<<<dim3(1024, 8), 256, 0, stream>>>(inputs, qg, wt, qkv_b, btab, out);
        proj_mfma<<<50176 / 16, 256, 0, stream>>>(wt, proj_b, out);
    } else {
        attn2_fp32<<<dim3(1024, 8), 256, 0, stream>>>(inputs, qg, qkv_w, qkv_b, btab, out);
        proj16_fp32<<<50176 / 16, 256, 0, stream>>>(proj_w, proj_b, out);
    }
}

// Round 6
// 936.612 us; speedup vs baseline: 1.7389x; 1.7389x over previous
//
#include <hip/hip_runtime.h>

// ---------------------------------------------------------------------------
// Round 10: B-operand through LDS in fragment order.
// Round 9's stall: per-lane per-ks B-fragment GLOBAL loads (64 KB/block/ks of
// L2 traffic, latency exposed at each barrier) -> MfmaUtil 7%. Fix:
//   - prep_wt writes weight tables in wave-fragment-linear order:
//     slab[hi/lo][n][lane][8] (16 KB per K-step) -> GLL-stageable contiguous,
//     conflict-free ds_read_b128 per lane.
//   - attn: per-ks slab double-buffered in LDS (union'd with S_s: disjoint
//     live ranges) -> 72.8 KB LDS, 2 blocks/CU.
//   - proj: 64-row blocks, full 512 cols (in-place race-free), ks-outer /
//     cs-inner-unrolled, acc[32] static, 4-slab pipeline.
// Numerics unchanged from round 9 (hi/lo bf16 split, fp32 softmax/PV).
// ---------------------------------------------------------------------------

typedef unsigned int   u32;
typedef unsigned short u16;
typedef __attribute__((ext_vector_type(8))) short bf16x8;
typedef __attribute__((ext_vector_type(4))) float f32x4;
typedef __attribute__((address_space(3))) void lds_void;
typedef const __attribute__((address_space(1))) void glb_void;

#define MFMA __builtin_amdgcn_mfma_f32_16x16x32_bf16

__device__ __forceinline__ void cp16_async(const void* g, void* lds_wave_base) {
    __builtin_amdgcn_global_load_lds((glb_void*)g, (lds_void*)lds_wave_base, 16, 0, 0);
}

// Stage one contiguous 16 KB fragment slab (8192 u16) into LDS via GLL.
__device__ __forceinline__ void stageB(const u16* src, u16* dst, int t) {
#pragma unroll
    for (int it = 0; it < 4; ++it) {
        const int o = t + (it << 8);         // 16B unit id, 0..1023
        const int wb = o & ~63;              // wave-uniform unit base
        cp16_async(src + ((size_t)o << 3), dst + ((size_t)wb << 3));
    }
}

// RNE f32 -> bf16 hi, then RNE bf16 of the remainder.
#define CVT1(x, he, le) {                                                      \
    u32 _u = __float_as_uint(x);                                               \
    u32 _hb = (_u + 0x7FFFu + ((_u >> 16) & 1u)) >> 16;                        \
    float _hf = __uint_as_float(_hb << 16);                                    \
    float _lf = (x) - _hf;                                                     \
    u32 _ul = __float_as_uint(_lf);                                            \
    he = (short)(u16)_hb;                                                      \
    le = (short)(u16)((_ul + 0x7FFFu + ((_ul >> 16) & 1u)) >> 16); }

__device__ __forceinline__ void cvt8(const float4 a0, const float4 a1,
                                     bf16x8& h, bf16x8& l) {
    CVT1(a0.x, h[0], l[0])  CVT1(a0.y, h[1], l[1])
    CVT1(a0.z, h[2], l[2])  CVT1(a0.w, h[3], l[3])
    CVT1(a1.x, h[4], l[4])  CVT1(a1.y, h[5], l[5])
    CVT1(a1.z, h[6], l[6])  CVT1(a1.w, h[7], l[7])
}

// ---------------------------------------------------------------------------
// prep: fragment-order hi/lo weight tables. ws layout (u16):
//   [0)        attn: [hg(8)][ks(16)] slabs of [hl(2)][n(8)][lane(64)][e(8)]
//   [1048576)  proj: [ks(16)][cs(4)] slabs, same inner layout. Total 3 MiB.
// Reads are fully coalesced (tid == flat source index).
// ---------------------------------------------------------------------------
__global__ __launch_bounds__(256) void prep_wt(const float* __restrict__ qkv_w,
                                               const float* __restrict__ proj_w,
                                               u16* __restrict__ ws) {
    const int tid = blockIdx.x * 256 + threadIdx.x;   // 0..786431
    if (tid < 524288) {                               // qkv_w [512][1024]
        const int k = tid >> 10, col = tid & 1023;
        const float x = qkv_w[tid];
        short h, l; CVT1(x, h, l)
        const int ks = k >> 5, kl = k & 31, lhi = kl >> 3, e = kl & 7;
        int hg, n, lr;
        if (col < 512) { hg = col >> 6; n = (col >> 4) & 3; lr = col & 15; }
        else { const int c2 = col - 512; hg = c2 >> 6; n = 4 + ((c2 >> 4) & 3); lr = c2 & 15; }
        const int lane = (lhi << 4) + lr;
        const size_t base = ((size_t)(hg * 16 + ks) << 13) + (n << 9) + (lane << 3) + e;
        ws[base] = (u16)h; ws[base + 4096] = (u16)l;
    } else {                                          // proj_w [512][512]
        const int f = tid - 524288;
        const int k = f >> 9, col = f & 511;
        const float x = proj_w[f];
        short h, l; CVT1(x, h, l)
        const int ks = k >> 5, kl = k & 31, lhi = kl >> 3, e = kl & 7;
        const int cs = col >> 7, n = (col >> 4) & 7, lr = col & 15;
        const int lane = (lhi << 4) + lr;
        const size_t base = 1048576 + ((size_t)((ks << 2) + cs) << 13) + (n << 9) + (lane << 3) + e;
        ws[base] = (u16)h; ws[base + 4096] = (u16)l;
    }
}

// ---------------------------------------------------------------------------
// attn2_mfma: block = (window, head-pair). Phase 1 (kv tile 49x128) on MFMA
// with LDS-staged B slabs; phases 2-4 = proven fp32 wave-softmax structure.
// ---------------------------------------------------------------------------
union alignas(16) PhaseMem {
    unsigned short B[2][8192];   // phase 1: B slab double-buffer (32 KB)
    float S[49][50];             // phases 2-4: P matrix (9.8 KB)
};

__global__ __launch_bounds__(256, 2) void attn2_mfma(
    const float* __restrict__ inp, const float* __restrict__ qg,
    const u16* __restrict__ wt, const float* __restrict__ b,
    const float* __restrict__ bt, float* __restrict__ out) {
    __shared__ float kv_s[49][132];     // 25872 B
    __shared__ float inp_s[2][49][36];  // 14112 B; A chunks / q slices
    __shared__ PhaseMem us;             // 32768 B    -> total 72752 B

    const int win = blockIdx.x;
    const int hg  = blockIdx.y;          // head pair 0..7
    const int t   = threadIdx.x;
    const int wv  = t >> 6;              // wave id = M-tile id
    const int l   = t & 63;
    const int lr  = l & 15;
    const int lk  = l >> 4;
    const int lk8 = lk << 3;

    const float* ip = inp + (size_t)win * 49 * 512;

    const int o1 = t + 256;
    const bool has2 = (o1 < 392);
    const int sr0 = t >> 3,  sc0 = (t & 7) << 2;
    const int sr1 = o1 >> 3, sc1 = (o1 & 7) << 2;

    const int arow = min(16 * wv + lr, 48);   // clamp wave-3 pad rows
    const u16* tb = wt + ((size_t)(hg * 16) << 13);

    f32x4 acc[8];
#pragma unroll
    for (int n = 0; n < 8; ++n) acc[n] = (f32x4){0.f, 0.f, 0.f, 0.f};

    // prologue: slab 0 via GLL + input chunk 0 via regs
    stageB(tb, us.B[0], t);
    {
        float4 s0 = *(const float4*)(ip + (size_t)sr0 * 512 + sc0);
        float4 s1;
        if (has2) s1 = *(const float4*)(ip + (size_t)sr1 * 512 + sc1);
        *(float4*)&inp_s[0][sr0][sc0] = s0;
        if (has2) *(float4*)&inp_s[0][sr1][sc1] = s1;
    }
    __syncthreads();

    for (int ks = 0; ks < 16; ++ks) {
        const int cur = ks & 1;
        float4 st0, st1;
        if (ks < 15) {   // issue next input chunk + next B slab BEFORE compute
            const float* src = ip + ((ks + 1) << 5);
            st0 = *(const float4*)(src + (size_t)sr0 * 512 + sc0);
            if (has2) st1 = *(const float4*)(src + (size_t)sr1 * 512 + sc1);
            stageB(tb + ((size_t)(ks + 1) << 13), us.B[cur ^ 1], t);
        }
        float4 a0 = *(const float4*)&inp_s[cur][arow][lk8];
        float4 a1 = *(const float4*)&inp_s[cur][arow][lk8 + 4];
        bf16x8 ah, al; cvt8(a0, a1, ah, al);

        const u16* bp = us.B[cur] + (l << 3);
        bf16x8 Bh[8];
#pragma unroll
        for (int n = 0; n < 8; ++n) Bh[n] = *(const bf16x8*)(bp + (n << 9));
#pragma unroll
        for (int n = 0; n < 8; ++n) acc[n] = MFMA(ah, Bh[n], acc[n], 0, 0, 0);
#pragma unroll
        for (int n = 0; n < 8; ++n) acc[n] = MFMA(al, Bh[n], acc[n], 0, 0, 0);
#pragma unroll
        for (int n = 0; n < 8; ++n) {
            bf16x8 Bl = *(const bf16x8*)(bp + 4096 + (n << 9));
            acc[n] = MFMA(ah, Bl, acc[n], 0, 0, 0);
        }
        if (ks < 15) {
            *(float4*)&inp_s[cur ^ 1][sr0][sc0] = st0;
            if (has2) *(float4*)&inp_s[cur ^ 1][sr1][sc1] = st1;
        }
        __syncthreads();
    }

    // writeback kv tile (+bias); D: row = 16*wv + 4*lk + r, col = n*16 + lr
#pragma unroll
    for (int n = 0; n < 8; ++n) {
        const int colg = (n < 4) ? (hg * 64 + n * 16 + lr)
                                 : (512 + hg * 64 + (n - 4) * 16 + lr);
        const float bias = b[colg];
        const int cloc = n * 16 + lr;
#pragma unroll
        for (int r = 0; r < 4; ++r) {
            const int row = 16 * wv + 4 * lk + r;
            if (row < 49) kv_s[row][cloc] = acc[n][r] + bias;
        }
    }

    // stage BOTH q head slices
    const float* qwin = qg + (size_t)(win >> 4) * 49 * 512 + (hg << 6);
    {
        float4 q00 = *(const float4*)(qwin + (size_t)sr0 * 512 + sc0);
        float4 q10 = *(const float4*)(qwin + 32 + (size_t)sr0 * 512 + sc0);
        float4 q01, q11;
        if (has2) {
            q01 = *(const float4*)(qwin + (size_t)sr1 * 512 + sc1);
            q11 = *(const float4*)(qwin + 32 + (size_t)sr1 * 512 + sc1);
        }
        *(float4*)&inp_s[0][sr0][sc0] = q00;
        *(float4*)&inp_s[1][sr0][sc0] = q10;
        if (has2) {
            *(float4*)&inp_s[0][sr1][sc1] = q01;
            *(float4*)&inp_s[1][sr1][sc1] = q11;
        }
    }
    __syncthreads();

    // ---- phases 2-4 per head (proven structure) --------------------------
    const int j  = l;
    const int jj = (j < 49) ? j : 48;
    const int jh = jj / 7, jw = jj - jh * 7;
    const int c_j = jh * 13 + jw;

    for (int hh = 0; hh < 2; ++hh) {
        const int H = (hg << 1) + hh;

        float4 kreg[8];
#pragma unroll
        for (int d4 = 0; d4 < 8; ++d4)
            kreg[d4] = *(const float4*)&kv_s[jj][(hh << 5) + (d4 << 2)];

        for (int i = wv; i < 49; i += 4) {
            const int ih = i / 7, iw = i - ih * 7;
            const int r_i = ih * 13 + iw + 84;
            float s = 0.f;
#pragma unroll
            for (int d4 = 0; d4 < 8; ++d4) {
                float4 qv = *(const float4*)&inp_s[hh][i][d4 << 2];  // broadcast
                s = fmaf(qv.x, kreg[d4].x, s); s = fmaf(qv.y, kreg[d4].y, s);
                s = fmaf(qv.z, kreg[d4].z, s); s = fmaf(qv.w, kreg[d4].w, s);
            }
            s = s * 0.17677669529663687f + bt[(r_i - c_j) * 16 + H];
            if (j >= 49) s = -1e30f;
            float mx = s;
#pragma unroll
            for (int m = 32; m; m >>= 1) mx = fmaxf(mx, __shfl_xor(mx, m));
            float e = __expf(s - mx);
            float sum = e;
#pragma unroll
            for (int m = 32; m; m >>= 1) sum += __shfl_xor(sum, m);
            float p = e * (1.f / sum);
            if (j < 49) us.S[i][j] = p;
        }
        __syncthreads();

        for (int o = t; o < 392; o += 256) {
            int i = o >> 3, dd = (o & 7) << 2;
            float4 a4 = make_float4(0.f, 0.f, 0.f, 0.f);
#pragma unroll 7
            for (int jq = 0; jq < 49; ++jq) {
                float p = us.S[i][jq];
                float4 vf = *(const float4*)&kv_s[jq][64 + (hh << 5) + dd];
                a4.x = fmaf(p, vf.x, a4.x); a4.y = fmaf(p, vf.y, a4.y);
                a4.z = fmaf(p, vf.z, a4.z); a4.w = fmaf(p, vf.w, a4.w);
            }
            *(float4*)(out + ((size_t)win * 49 + i) * 512 + (H << 5) + dd) = a4;
        }
        __syncthreads();
    }
}

// ---------------------------------------------------------------------------
// proj_mfma: 64 rows/block, ALL 512 cols (in-place race-free). Wave wv owns
// rows 16wv..16wv+15; ks outer (X chunk staged once), cs 0..3 unrolled inner
// with a 4-slab LDS pipeline; acc[32] statically indexed.
// ---------------------------------------------------------------------------
__global__ __launch_bounds__(256, 2) void proj_mfma(
    const u16* __restrict__ wt, const float* __restrict__ pb,
    float* __restrict__ io) {
    __shared__ alignas(16) u16 Bs[2][8192];  // 32768 B
    __shared__ float X_s[2][64][36];         // 18432 B  -> total 51200 B
    const int m0 = blockIdx.x << 6;
    const int t  = threadIdx.x;
    const int wv = t >> 6, l = t & 63, lr = l & 15, lk = l >> 4, lk8 = lk << 3;
    const int arow = (wv << 4) + lr;

    const float* xp = io + (size_t)m0 * 512;
    const int sr0 = t >> 3,         sc0 = (t & 7) << 2;          // 512 f4, 2/thread
    const int sr1 = (t + 256) >> 3, sc1 = ((t + 256) & 7) << 2;
    const u16* tb = wt + 1048576;

    f32x4 acc[32];
#pragma unroll
    for (int n = 0; n < 32; ++n) acc[n] = (f32x4){0.f, 0.f, 0.f, 0.f};

    // prologue: X chunk 0 + slab 0
    stageB(tb, Bs[0], t);
    {
        float4 s0 = *(const float4*)(xp + (size_t)sr0 * 512 + sc0);
        float4 s1 = *(const float4*)(xp + (size_t)sr1 * 512 + sc1);
        *(float4*)&X_s[0][sr0][sc0] = s0;
        *(float4*)&X_s[0][sr1][sc1] = s1;
    }
    __syncthreads();

    for (int ks = 0; ks < 16; ++ks) {
        const int cur = ks & 1;
        float4 xa, xb;
        if (ks < 15) {
            const float* src = xp + ((ks + 1) << 5);
            xa = *(const float4*)(src + (size_t)sr0 * 512 + sc0);
            xb = *(const float4*)(src + (size_t)sr1 * 512 + sc1);
        }
        float4 a0 = *(const float4*)&X_s[cur][arow][lk8];
        float4 a1 = *(const float4*)&X_s[cur][arow][lk8 + 4];
        bf16x8 ah, al; cvt8(a0, a1, ah, al);

#pragma unroll
        for (int cs = 0; cs < 4; ++cs) {
            const int s = (ks << 2) + cs;
            if (s < 63) stageB(tb + ((size_t)(s + 1) << 13), Bs[(s + 1) & 1], t);
            const u16* bp = Bs[s & 1] + (l << 3);
            bf16x8 Bh[8];
#pragma unroll
            for (int n = 0; n < 8; ++n) Bh[n] = *(const bf16x8*)(bp + (n << 9));
#pragma unroll
            for (int n = 0; n < 8; ++n)
                acc[(cs << 3) + n] = MFMA(ah, Bh[n], acc[(cs << 3) + n], 0, 0, 0);
#pragma unroll
            for (int n = 0; n < 8; ++n)
                acc[(cs << 3) + n] = MFMA(al, Bh[n], acc[(cs << 3) + n], 0, 0, 0);
#pragma unroll
            for (int n = 0; n < 8; ++n) {
                bf16x8 Bl = *(const bf16x8*)(bp + 4096 + (n << 9));
                acc[(cs << 3) + n] = MFMA(ah, Bl, acc[(cs << 3) + n], 0, 0, 0);
            }
            if (cs == 3 && ks < 15) {   // write next X chunk before the barrier
                *(float4*)&X_s[cur ^ 1][sr0][sc0] = xa;
                *(float4*)&X_s[cur ^ 1][sr1][sc1] = xb;
            }
            __syncthreads();
        }
    }

    // epilogue: row = m0 + 16wv + 4lk + r, col = cs*128 + n*16 + lr
#pragma unroll
    for (int cs = 0; cs < 4; ++cs) {
#pragma unroll
        for (int n = 0; n < 8; ++n) {
            const int col = (cs << 7) + (n << 4) + lr;
            const float bias = pb[col];
#pragma unroll
            for (int r = 0; r < 4; ++r)
                io[(size_t)(m0 + (wv << 4) + (lk << 2) + r) * 512 + col] =
                    acc[(cs << 3) + n][r] + bias;
        }
    }
}

// ===========================================================================
// fp32 fallback path (round-8 kernels) — used if ws_size < 3 MiB.
// ===========================================================================
__device__ __forceinline__ void stage49x32(const float* src, float* dst, int t) {
#pragma unroll
    for (int it = 0; it < 2; ++it) {
        const int o = t + (it << 8);
        if (o < 392) {
            const int wb = o & ~63;
            cp16_async(src + (size_t)(o >> 3) * 512 + ((o & 7) << 2),
                       dst + (wb << 2));
        }
    }
}

#define FMA4(accv, f, w0, w1, w2, w3)                                          \
  accv.x = fmaf(f.x, w0.x, accv.x); accv.x = fmaf(f.y, w1.x, accv.x);          \
  accv.x = fmaf(f.z, w2.x, accv.x); accv.x = fmaf(f.w, w3.x, accv.x);          \
  accv.y = fmaf(f.x, w0.y, accv.y); accv.y = fmaf(f.y, w1.y, accv.y);          \
  accv.y = fmaf(f.z, w2.y, accv.y); accv.y = fmaf(f.w, w3.y, accv.y);          \
  accv.z = fmaf(f.x, w0.z, accv.z); accv.z = fmaf(f.y, w1.z, accv.z);          \
  accv.z = fmaf(f.z, w2.z, accv.z); accv.z = fmaf(f.w, w3.z, accv.z);          \
  accv.w = fmaf(f.x, w0.w, accv.w); accv.w = fmaf(f.y, w1.w, accv.w);          \
  accv.w = fmaf(f.z, w2.w, accv.w); accv.w = fmaf(f.w, w3.w, accv.w);

__global__ __launch_bounds__(256, 3) void attn2_fp32(
    const float* __restrict__ inp, const float* __restrict__ qg,
    const float* __restrict__ W, const float* __restrict__ b,
    const float* __restrict__ bt, float* __restrict__ out) {
    __shared__ float kv_s[56][132];
    __shared__ float S_s[49][50];
    __shared__ float inp_s[2][56][32];
    const int win = blockIdx.x, hg = blockIdx.y, t = threadIdx.x;
    const int c4 = t & 31, rg = t >> 5, wv = t >> 6, j = t & 63;
    const int colbase = (c4 < 16) ? (hg * 64 + (c4 << 2))
                                  : (512 + hg * 64 + ((c4 - 16) << 2));
    const float* ip = inp + (size_t)win * 49 * 512;
    float4 acc[7];
#pragma unroll
    for (int rr = 0; rr < 7; ++rr) acc[rr] = make_float4(0.f, 0.f, 0.f, 0.f);
    const float4 bias4 = *(const float4*)(b + colbase);
    stage49x32(ip, &inp_s[0][0][0], t);
    __syncthreads();
    for (int kc = 0; kc < 512; kc += 32) {
        const int cur = (kc >> 5) & 1;
        if (kc + 32 < 512) stage49x32(ip + kc + 32, &inp_s[cur ^ 1][0][0], t);
        const float* Wp = W + ((size_t)kc << 10) + colbase;
#pragma unroll
        for (int k4 = 0; k4 < 8; ++k4) {
            const float* wr = Wp + ((size_t)(k4 << 2) << 10);
            float4 w0 = *(const float4*)(wr);
            float4 w1 = *(const float4*)(wr + 1024);
            float4 w2 = *(const float4*)(wr + 2048);
            float4 w3 = *(const float4*)(wr + 3072);
#pragma unroll
            for (int rr = 0; rr < 7; ++rr) {
                float4 f = *(const float4*)&inp_s[cur][rg + (rr << 3)][k4 << 2];
                FMA4(acc[rr], f, w0, w1, w2, w3)
            }
        }
        __syncthreads();
    }
#pragma unroll
    for (int rr = 0; rr < 7; ++rr) {
        const int r = rg + (rr << 3);
        float4 res = make_float4(acc[rr].x + bias4.x, acc[rr].y + bias4.y,
                                 acc[rr].z + bias4.z, acc[rr].w + bias4.w);
        *(float4*)&kv_s[r][c4 << 2] = res;
    }
    const float* qwin = qg + (size_t)(win >> 4) * 49 * 512 + (hg << 6);
    stage49x32(qwin, &inp_s[0][0][0], t);
    __syncthreads();
    const int jj = (j < 49) ? j : 48;
    const int jh = jj / 7, jw = jj - jh * 7;
    const int c_j = jh * 13 + jw;
    for (int hh = 0; hh < 2; ++hh) {
        const int H = (hg << 1) + hh;
        const int qb = hh;
        if (hh == 0) stage49x32(qwin + 32, &inp_s[1][0][0], t);
        float4 kreg[8];
#pragma unroll
        for (int d4 = 0; d4 < 8; ++d4)
            kreg[d4] = *(const float4*)&kv_s[jj][(hh << 5) + (d4 << 2)];
        for (int i = wv; i < 49; i += 4) {
            const int ih = i / 7, iw = i - ih * 7;
            const int r_i = ih * 13 + iw + 84;
            float s = 0.f;
#pragma unroll
            for (int d4 = 0; d4 < 8; ++d4) {
                float4 qv = *(const float4*)&inp_s[qb][i][d4 << 2];
                s = fmaf(qv.x, kreg[d4].x, s); s = fmaf(qv.y, kreg[d4].y, s);
                s = fmaf(qv.z, kreg[d4].z, s); s = fmaf(qv.w, kreg[d4].w, s);
            }
            s = s * 0.17677669529663687f + bt[(r_i - c_j) * 16 + H];
            if (j >= 49) s = -1e30f;
            float mx = s;
#pragma unroll
            for (int m = 32; m; m >>= 1) mx = fmaxf(mx, __shfl_xor(mx, m));
            float e = __expf(s - mx);
            float sum = e;
#pragma unroll
            for (int m = 32; m; m >>= 1) sum += __shfl_xor(sum, m);
            float p = e * (1.f / sum);
            if (j < 49) S_s[i][j] = p;
        }
        __syncthreads();
        for (int o = t; o < 392; o += 256) {
            int i = o >> 3, dd = (o & 7) << 2;
            float4 a4 = make_float4(0.f, 0.f, 0.f, 0.f);
#pragma unroll 7
            for (int jq = 0; jq < 49; ++jq) {
                float p = S_s[i][jq];
                float4 vf = *(const float4*)&kv_s[jq][64 + (hh << 5) + dd];
                a4.x = fmaf(p, vf.x, a4.x); a4.y = fmaf(p, vf.y, a4.y);
                a4.z = fmaf(p, vf.z, a4.z); a4.w = fmaf(p, vf.w, a4.w);
            }
            *(float4*)(out + ((size_t)win * 49 + i) * 512 + (H << 5) + dd) = a4;
        }
        __syncthreads();
    }
}

__global__ __launch_bounds__(256, 4) void proj16_fp32(
    const float* __restrict__ pw, const float* __restrict__ pb,
    float* __restrict__ io) {
    __shared__ float X_s[16][512];
    const int m0 = blockIdx.x << 4;
    const int t = threadIdx.x;
    const int c4 = (t & 127) << 2;
    const int rg = t >> 7;
    const float* xsrc = io + (size_t)m0 * 512;
#pragma unroll
    for (int it = 0; it < 8; ++it) {
        const int o = t + (it << 8);
        const int wb = o & ~63;
        cp16_async(xsrc + ((size_t)o << 2), &X_s[0][0] + (wb << 2));
    }
    __syncthreads();
    const float4 bias = *(const float4*)(pb + c4);
    float4 acc[8];
#pragma unroll
    for (int r = 0; r < 8; ++r) acc[r] = bias;
    const float* wp = pw + c4;
    float4 w0 = *(const float4*)(wp);
    float4 w1 = *(const float4*)(wp + 512);
    float4 w2 = *(const float4*)(wp + 1024);
    float4 w3 = *(const float4*)(wp + 1536);
    for (int k4 = 0; k4 < 127; ++k4) {
        const float* wn = wp + (((size_t)k4 + 1) << 11);
        const float4 n0 = *(const float4*)(wn);
        const float4 n1 = *(const float4*)(wn + 512);
        const float4 n2 = *(const float4*)(wn + 1024);
        const float4 n3 = *(const float4*)(wn + 1536);
#pragma unroll
        for (int r = 0; r < 8; ++r) {
            const float4 f = *(const float4*)&X_s[(rg << 3) + r][k4 << 2];
            FMA4(acc[r], f, w0, w1, w2, w3)
        }
        w0 = n0; w1 = n1; w2 = n2; w3 = n3;
    }
#pragma unroll
    for (int r = 0; r < 8; ++r) {
        const float4 f = *(const float4*)&X_s[(rg << 3) + r][127 << 2];
        FMA4(acc[r], f, w0, w1, w2, w3)
    }
#pragma unroll
    for (int r = 0; r < 8; ++r)
        *(float4*)(io + ((size_t)(m0 + (rg << 3) + r)) * 512 + c4) = acc[r];
}

// ---------------------------------------------------------------------------
extern "C" void kernel_launch(void* const* d_in, const int* in_sizes, int n_in,
                              void* d_out, int out_size, void* d_ws, size_t ws_size,
                              hipStream_t stream) {
    const float* inputs = (const float*)d_in[0];   // [1024*49, 512]
    const float* qg     = (const float*)d_in[1];   // [64*49, 512]
    const float* qkv_w  = (const float*)d_in[2];   // [512, 1024]
    const float* qkv_b  = (const float*)d_in[3];   // [1024]
    const float* btab   = (const float*)d_in[4];   // [169, 16]
    const float* proj_w = (const float*)d_in[5];   // [512, 512]
    const float* proj_b = (const float*)d_in[6];   // [512]
    float* out = (float*)d_out;                    // [1024*49, 512]

    const size_t WS_NEED = 1572864ull * sizeof(unsigned short);  // 3 MiB
    if (d_ws != nullptr && ws_size >= WS_NEED) {
        u16* wt = (u16*)d_ws;
        prep_wt<<<3072, 256, 0, stream>>>(qkv_w, proj_w, wt);
        attn2_mfma<<<dim3(1024, 8), 256, 0, stream>>>(inputs, qg, wt, qkv_b, btab, out);
        proj_mfma<<<784, 256, 0, stream>>>(wt, proj_b, out);
    } else {
        attn2_fp32<<<dim3(1024, 8), 256, 0, stream>>>(inputs, qg, qkv_w, qkv_b, btab, out);
        proj16_fp32<<<50176 / 16, 256, 0, stream>>>(proj_w, proj_b, out);
    }
}

// Round 7
// 748.688 us; speedup vs baseline: 2.1753x; 1.2510x over previous
//
#include <hip/hip_runtime.h>

// ---------------------------------------------------------------------------
// Round 11: LDS-traffic + fp32-leftover attack.
//  - Phase 1: A pre-converted to hi/lo bf16 at staging (cooperative, once);
//    2M x 2N wave split -> 12 ds_read_b128 per wave per ks (was 18 + cvt8).
//  - Phases 2-4 on MFMA: epilogue writes K/V (V transposed) as hi/lo bf16
//    fragments straight from acc regs; QK^T and PV are 12 MFMAs each per
//    wave per head; softmax in D-fragment registers (16-lane shfl reduce).
//  - All pads masked/zeroed so no NaN enters MFMA operands.
//  proj/prep/fallback unchanged from round 10 (proven).
// ---------------------------------------------------------------------------

typedef unsigned int   u32;
typedef unsigned short u16;
typedef __attribute__((ext_vector_type(8))) short bf16x8;
typedef __attribute__((ext_vector_type(4))) float f32x4;
typedef __attribute__((ext_vector_type(4))) u16   u16x4;
typedef __attribute__((address_space(3))) void lds_void;
typedef const __attribute__((address_space(1))) void glb_void;

#define MFMA __builtin_amdgcn_mfma_f32_16x16x32_bf16

__device__ __forceinline__ void cp16_async(const void* g, void* lds_wave_base) {
    __builtin_amdgcn_global_load_lds((glb_void*)g, (lds_void*)lds_wave_base, 16, 0, 0);
}

// Stage one contiguous 16 KB fragment slab (8192 u16) into LDS via GLL.
__device__ __forceinline__ void stageB(const u16* src, u16* dst, int t) {
#pragma unroll
    for (int it = 0; it < 4; ++it) {
        const int o = t + (it << 8);
        const int wb = o & ~63;
        cp16_async(src + ((size_t)o << 3), dst + ((size_t)wb << 3));
    }
}

// RNE f32 -> bf16 hi, then RNE bf16 of the remainder.
#define CVT1(x, he, le) {                                                      \
    u32 _u = __float_as_uint(x);                                               \
    u32 _hb = (_u + 0x7FFFu + ((_u >> 16) & 1u)) >> 16;                        \
    float _hf = __uint_as_float(_hb << 16);                                    \
    float _lf = (x) - _hf;                                                     \
    u32 _ul = __float_as_uint(_lf);                                            \
    he = (short)(u16)_hb;                                                      \
    le = (short)(u16)((_ul + 0x7FFFu + ((_ul >> 16) & 1u)) >> 16); }

__device__ __forceinline__ void cvt_wr4(const float4 v, u16* hi, u16* lo) {
    short h0, l0, h1, l1, h2, l2, h3, l3;
    CVT1(v.x, h0, l0) CVT1(v.y, h1, l1) CVT1(v.z, h2, l2) CVT1(v.w, h3, l3)
    u16x4 H = {(u16)h0, (u16)h1, (u16)h2, (u16)h3};
    u16x4 L = {(u16)l0, (u16)l1, (u16)l2, (u16)l3};
    *(u16x4*)hi = H; *(u16x4*)lo = L;
}

// ---------------------------------------------------------------------------
// prep: fragment-order hi/lo weight tables (unchanged from round 10).
// ws layout (u16): [0) attn [hg(8)][ks(16)] slabs [hl][n(8)][lane(64)][e(8)];
//                  [1048576) proj [ks(16)][cs(4)] slabs. Total 3 MiB.
// ---------------------------------------------------------------------------
__global__ __launch_bounds__(256) void prep_wt(const float* __restrict__ qkv_w,
                                               const float* __restrict__ proj_w,
                                               u16* __restrict__ ws) {
    const int tid = blockIdx.x * 256 + threadIdx.x;
    if (tid < 524288) {                               // qkv_w [512][1024]
        const int k = tid >> 10, col = tid & 1023;
        const float x = qkv_w[tid];
        short h, l; CVT1(x, h, l)
        const int ks = k >> 5, kl = k & 31, lhi = kl >> 3, e = kl & 7;
        int hg, n, lr;
        if (col < 512) { hg = col >> 6; n = (col >> 4) & 3; lr = col & 15; }
        else { const int c2 = col - 512; hg = c2 >> 6; n = 4 + ((c2 >> 4) & 3); lr = c2 & 15; }
        const int lane = (lhi << 4) + lr;
        const size_t base = ((size_t)(hg * 16 + ks) << 13) + (n << 9) + (lane << 3) + e;
        ws[base] = (u16)h; ws[base + 4096] = (u16)l;
    } else {                                          // proj_w [512][512]
        const int f = tid - 524288;
        const int k = f >> 9, col = f & 511;
        const float x = proj_w[f];
        short h, l; CVT1(x, h, l)
        const int ks = k >> 5, kl = k & 31, lhi = kl >> 3, e = kl & 7;
        const int cs = col >> 7, n = (col >> 4) & 7, lr = col & 15;
        const int lane = (lhi << 4) + lr;
        const size_t base = 1048576 + ((size_t)((ks << 2) + cs) << 13) + (n << 9) + (lane << 3) + e;
        ws[base] = (u16)h; ws[base + 4096] = (u16)l;
    }
}

// ---------------------------------------------------------------------------
// attn kernel. Phase-1 region and phase-2 region share LDS via union.
// ---------------------------------------------------------------------------
struct Ph1T {
    u16 A[2][2][64][40];              // [buf][hl][row][40]: 40960 B (rows 49+ pad)
    alignas(16) u16 B[2][8192];       // B slab dbuf: 32768 B
};
struct Ph2T {
    u16 Kb[2][2][64][40];             // [head][hl][j][d]: 20480 B
    u16 Vb[2][2][32][72];             // [head][hl][d][j]: 18432 B
    u16 Qb[2][64][40];                // [hl][i][d]:       10240 B
    u16 Pb[2][64][72];                // [hl][i][j]:       18432 B
};
union alignas(16) RegionT { Ph1T p1; Ph2T p2; };

__global__ __launch_bounds__(256, 2) void attn2_mfma(
    const float* __restrict__ inp, const float* __restrict__ qg,
    const u16* __restrict__ wt, const float* __restrict__ b,
    const float* __restrict__ bt, float* __restrict__ out) {
    __shared__ RegionT rg;            // 73728 B -> 2 blocks/CU

    const int win = blockIdx.x;
    const int hg  = blockIdx.y;       // head pair
    const int t   = threadIdx.x;
    const int wv  = t >> 6;           // wave 0..3
    const int l   = t & 63;
    const int lr  = l & 15;
    const int lk  = l >> 4;
    const int lk8 = lk << 3;
    const int wm  = wv >> 1;          // phase-1 M half
    const int wn  = wv & 1;           // phase-1 N half (0:k, 1:v)

    const float* ip = inp + (size_t)win * 49 * 512;
    const u16* tb = wt + ((size_t)(hg * 16) << 13);

    const int o1 = t + 256;
    const bool has2 = (o1 < 392);
    const int sr0 = t >> 3,  sc0 = (t & 7) << 2;
    const int sr1 = o1 >> 3, sc1 = (o1 & 7) << 2;

    const int r0 = (wm << 5) + lr;    // A row, M-tile 0 (tile 1 = +16)

    f32x4 acc[2][4];
#pragma unroll
    for (int mt = 0; mt < 2; ++mt)
#pragma unroll
        for (int nt = 0; nt < 4; ++nt) acc[mt][nt] = (f32x4){0.f, 0.f, 0.f, 0.f};

    // ---- phase 1 prologue ------------------------------------------------
    stageB(tb, rg.p1.B[0], t);
    {
        float4 s0 = *(const float4*)(ip + (size_t)sr0 * 512 + sc0);
        float4 s1;
        if (has2) s1 = *(const float4*)(ip + (size_t)sr1 * 512 + sc1);
        cvt_wr4(s0, &rg.p1.A[0][0][sr0][sc0], &rg.p1.A[0][1][sr0][sc0]);
        if (has2) cvt_wr4(s1, &rg.p1.A[0][0][sr1][sc1], &rg.p1.A[0][1][sr1][sc1]);
    }
    __syncthreads();

    // ---- phase 1: kv tile GEMM ------------------------------------------
    for (int ks = 0; ks < 16; ++ks) {
        const int cur = ks & 1;
        float4 st0, st1;
        if (ks < 15) {
            const float* src = ip + ((ks + 1) << 5);
            st0 = *(const float4*)(src + (size_t)sr0 * 512 + sc0);
            if (has2) st1 = *(const float4*)(src + (size_t)sr1 * 512 + sc1);
            stageB(tb + ((size_t)(ks + 1) << 13), rg.p1.B[cur ^ 1], t);
        }
        bf16x8 ah0 = *(const bf16x8*)&rg.p1.A[cur][0][r0][lk8];
        bf16x8 al0 = *(const bf16x8*)&rg.p1.A[cur][1][r0][lk8];
        bf16x8 ah1 = *(const bf16x8*)&rg.p1.A[cur][0][r0 + 16][lk8];
        bf16x8 al1 = *(const bf16x8*)&rg.p1.A[cur][1][r0 + 16][lk8];
        const u16* bp = rg.p1.B[cur] + ((wn << 2) << 9) + (l << 3);
#pragma unroll
        for (int nt = 0; nt < 4; ++nt) {
            bf16x8 Bh = *(const bf16x8*)(bp + (nt << 9));
            bf16x8 Bl = *(const bf16x8*)(bp + 4096 + (nt << 9));
            acc[0][nt] = MFMA(ah0, Bh, acc[0][nt], 0, 0, 0);
            acc[1][nt] = MFMA(ah1, Bh, acc[1][nt], 0, 0, 0);
            acc[0][nt] = MFMA(al0, Bh, acc[0][nt], 0, 0, 0);
            acc[1][nt] = MFMA(al1, Bh, acc[1][nt], 0, 0, 0);
            acc[0][nt] = MFMA(ah0, Bl, acc[0][nt], 0, 0, 0);
            acc[1][nt] = MFMA(ah1, Bl, acc[1][nt], 0, 0, 0);
        }
        if (ks < 15) {
            cvt_wr4(st0, &rg.p1.A[cur ^ 1][0][sr0][sc0], &rg.p1.A[cur ^ 1][1][sr0][sc0]);
            if (has2) cvt_wr4(st1, &rg.p1.A[cur ^ 1][0][sr1][sc1], &rg.p1.A[cur ^ 1][1][sr1][sc1]);
        }
        __syncthreads();
    }

    // ---- epilogue: acc (+bias) -> Kb / Vb as hi/lo bf16 fragments --------
    // Aliases phase-1 memory: all waves passed the final barrier above.
#pragma unroll
    for (int mt = 0; mt < 2; ++mt) {
#pragma unroll
        for (int nn = 0; nn < 4; ++nn) {
            const int colg = (wn ? 512 : 0) + hg * 64 + nn * 16 + lr;
            const float bias = b[colg];
            const int hh = nn >> 1;
            const int d  = ((nn & 1) << 4) + lr;
#pragma unroll
            for (int r = 0; r < 4; ++r) {
                const int jrow = (wm << 5) + (mt << 4) + (lk << 2) + r;
                const float v = acc[mt][nn][r] + bias;
                short h, lo_; CVT1(v, h, lo_)
                if (jrow >= 49) { h = 0; lo_ = 0; }   // zero pads: no NaN in MFMA
                if (wn == 0) {
                    rg.p2.Kb[hh][0][jrow][d] = (u16)h;
                    rg.p2.Kb[hh][1][jrow][d] = (u16)lo_;
                } else {
                    rg.p2.Vb[hh][0][d][jrow] = (u16)h;    // transposed
                    rg.p2.Vb[hh][1][d][jrow] = (u16)lo_;
                }
            }
        }
    }

    // ---- phases 2-4 per head, all on MFMA --------------------------------
    const float* qwin = qg + (size_t)(win >> 4) * 49 * 512 + (hg << 6);
    const float SCALE = 0.17677669529663687f;

    for (int hh = 0; hh < 2; ++hh) {
        const int H = (hg << 1) + hh;

        // Q convert: global fp32 -> Qb hi/lo (rows 0-48)
        for (int idx = t; idx < 1568; idx += 256) {
            const int jr = idx >> 5, d = idx & 31;
            const float x = qwin[(size_t)jr * 512 + (hh << 5) + d];
            short h, lo_; CVT1(x, h, lo_)
            rg.p2.Qb[0][jr][d] = (u16)h;
            rg.p2.Qb[1][jr][d] = (u16)lo_;
        }
        __syncthreads();   // Kb/Vb epilogue writes + Qb visible

        // QK^T: wave wv owns M-tile wv (i = 16wv + ...)
        bf16x8 qh = *(const bf16x8*)&rg.p2.Qb[0][(wv << 4) + lr][lk8];
        bf16x8 ql = *(const bf16x8*)&rg.p2.Qb[1][(wv << 4) + lr][lk8];
        f32x4 sacc[4];
#pragma unroll
        for (int nt = 0; nt < 4; ++nt) sacc[nt] = (f32x4){0.f, 0.f, 0.f, 0.f};
#pragma unroll
        for (int nt = 0; nt < 4; ++nt) {
            bf16x8 kh = *(const bf16x8*)&rg.p2.Kb[hh][0][(nt << 4) + lr][lk8];
            bf16x8 kl = *(const bf16x8*)&rg.p2.Kb[hh][1][(nt << 4) + lr][lk8];
            sacc[nt] = MFMA(qh, kh, sacc[nt], 0, 0, 0);
            sacc[nt] = MFMA(qh, kl, sacc[nt], 0, 0, 0);
            sacc[nt] = MFMA(ql, kh, sacc[nt], 0, 0, 0);
        }

        // bias + mask (D: row i = 16wv+4lk+r, col j = 16nt+lr)
        float sv[4][4];
#pragma unroll
        for (int nt = 0; nt < 4; ++nt) {
            const int j = (nt << 4) + lr;
            const int jh = j / 7, jw = j - jh * 7;
#pragma unroll
            for (int r = 0; r < 4; ++r) {
                const int i  = (wv << 4) + (lk << 2) + r;
                const int ic = (i < 49) ? i : 48;
                const int ih = ic / 7, iw = ic - ih * 7;
                sv[nt][r] = (j < 49)
                    ? sacc[nt][r] * SCALE + bt[((ih - jh + 6) * 13 + (iw - jw + 6)) * 16 + H]
                    : -1e30f;
            }
        }

        // softmax per row (16-lane shfl groups = fixed lk), P -> Pb hi/lo
#pragma unroll
        for (int r = 0; r < 4; ++r) {
            float m = fmaxf(fmaxf(sv[0][r], sv[1][r]), fmaxf(sv[2][r], sv[3][r]));
#pragma unroll
            for (int msk = 1; msk < 16; msk <<= 1) m = fmaxf(m, __shfl_xor(m, msk));
            const float e0 = __expf(sv[0][r] - m);
            const float e1 = __expf(sv[1][r] - m);
            const float e2 = __expf(sv[2][r] - m);
            const float e3 = __expf(sv[3][r] - m);
            float sum = e0 + e1 + e2 + e3;
#pragma unroll
            for (int msk = 1; msk < 16; msk <<= 1) sum += __shfl_xor(sum, msk);
            const float inv = 1.f / sum;
            const int i = (wv << 4) + (lk << 2) + r;
            float pv[4] = {e0 * inv, e1 * inv, e2 * inv, e3 * inv};
#pragma unroll
            for (int nt = 0; nt < 4; ++nt) {
                short h, lo_; CVT1(pv[nt], h, lo_)
                rg.p2.Pb[0][i][(nt << 4) + lr] = (u16)h;
                rg.p2.Pb[1][i][(nt << 4) + lr] = (u16)lo_;
            }
        }
        __syncthreads();

        // PV: X = P(64x64) . V(64x32); K-dim padded (P=0, V=0 beyond 49)
        f32x4 xacc[2];
        xacc[0] = (f32x4){0.f, 0.f, 0.f, 0.f};
        xacc[1] = (f32x4){0.f, 0.f, 0.f, 0.f};
#pragma unroll
        for (int kt = 0; kt < 2; ++kt) {
            bf16x8 ph = *(const bf16x8*)&rg.p2.Pb[0][(wv << 4) + lr][(kt << 5) + lk8];
            bf16x8 pl = *(const bf16x8*)&rg.p2.Pb[1][(wv << 4) + lr][(kt << 5) + lk8];
#pragma unroll
            for (int nt = 0; nt < 2; ++nt) {
                bf16x8 vh = *(const bf16x8*)&rg.p2.Vb[hh][0][(nt << 4) + lr][(kt << 5) + lk8];
                bf16x8 vl = *(const bf16x8*)&rg.p2.Vb[hh][1][(nt << 4) + lr][(kt << 5) + lk8];
                xacc[nt] = MFMA(ph, vh, xacc[nt], 0, 0, 0);
                xacc[nt] = MFMA(ph, vl, xacc[nt], 0, 0, 0);
                xacc[nt] = MFMA(pl, vh, xacc[nt], 0, 0, 0);
            }
        }

        // store X (rows i<49 only)
#pragma unroll
        for (int nt = 0; nt < 2; ++nt) {
#pragma unroll
            for (int r = 0; r < 4; ++r) {
                const int i = (wv << 4) + (lk << 2) + r;
                if (i < 49)
                    out[((size_t)win * 49 + i) * 512 + (H << 5) + (nt << 4) + lr] = xacc[nt][r];
            }
        }
        __syncthreads();   // Qb/Pb reused next head
    }
}

// ---------------------------------------------------------------------------
// proj_mfma (unchanged from round 10, proven green).
// ---------------------------------------------------------------------------
__global__ __launch_bounds__(256, 2) void proj_mfma(
    const u16* __restrict__ wt, const float* __restrict__ pb,
    float* __restrict__ io) {
    __shared__ alignas(16) u16 Bs[2][8192];
    __shared__ float X_s[2][64][36];
    const int m0 = blockIdx.x << 6;
    const int t  = threadIdx.x;
    const int wv = t >> 6, l = t & 63, lr = l & 15, lk = l >> 4, lk8 = lk << 3;
    const int arow = (wv << 4) + lr;

    const float* xp = io + (size_t)m0 * 512;
    const int sr0 = t >> 3,         sc0 = (t & 7) << 2;
    const int sr1 = (t + 256) >> 3, sc1 = ((t + 256) & 7) << 2;
    const u16* tb = wt + 1048576;

    f32x4 acc[32];
#pragma unroll
    for (int n = 0; n < 32; ++n) acc[n] = (f32x4){0.f, 0.f, 0.f, 0.f};

    stageB(tb, Bs[0], t);
    {
        float4 s0 = *(const float4*)(xp + (size_t)sr0 * 512 + sc0);
        float4 s1 = *(const float4*)(xp + (size_t)sr1 * 512 + sc1);
        *(float4*)&X_s[0][sr0][sc0] = s0;
        *(float4*)&X_s[0][sr1][sc1] = s1;
    }
    __syncthreads();

    for (int ks = 0; ks < 16; ++ks) {
        const int cur = ks & 1;
        float4 xa, xb;
        if (ks < 15) {
            const float* src = xp + ((ks + 1) << 5);
            xa = *(const float4*)(src + (size_t)sr0 * 512 + sc0);
            xb = *(const float4*)(src + (size_t)sr1 * 512 + sc1);
        }
        float4 a0 = *(const float4*)&X_s[cur][arow][lk8];
        float4 a1 = *(const float4*)&X_s[cur][arow][lk8 + 4];
        bf16x8 ah, al;
        {
            short h0,l0,h1,l1,h2,l2,h3,l3,h4,l4,h5,l5,h6,l6,h7,l7;
            CVT1(a0.x,h0,l0) CVT1(a0.y,h1,l1) CVT1(a0.z,h2,l2) CVT1(a0.w,h3,l3)
            CVT1(a1.x,h4,l4) CVT1(a1.y,h5,l5) CVT1(a1.z,h6,l6) CVT1(a1.w,h7,l7)
            ah = (bf16x8){h0,h1,h2,h3,h4,h5,h6,h7};
            al = (bf16x8){l0,l1,l2,l3,l4,l5,l6,l7};
        }

#pragma unroll
        for (int cs = 0; cs < 4; ++cs) {
            const int s = (ks << 2) + cs;
            if (s < 63) stageB(tb + ((size_t)(s + 1) << 13), Bs[(s + 1) & 1], t);
            const u16* bp = Bs[s & 1] + (l << 3);
            bf16x8 Bh[8];
#pragma unroll
            for (int n = 0; n < 8; ++n) Bh[n] = *(const bf16x8*)(bp + (n << 9));
#pragma unroll
            for (int n = 0; n < 8; ++n)
                acc[(cs << 3) + n] = MFMA(ah, Bh[n], acc[(cs << 3) + n], 0, 0, 0);
#pragma unroll
            for (int n = 0; n < 8; ++n)
                acc[(cs << 3) + n] = MFMA(al, Bh[n], acc[(cs << 3) + n], 0, 0, 0);
#pragma unroll
            for (int n = 0; n < 8; ++n) {
                bf16x8 Bl = *(const bf16x8*)(bp + 4096 + (n << 9));
                acc[(cs << 3) + n] = MFMA(ah, Bl, acc[(cs << 3) + n], 0, 0, 0);
            }
            if (cs == 3 && ks < 15) {
                *(float4*)&X_s[cur ^ 1][sr0][sc0] = xa;
                *(float4*)&X_s[cur ^ 1][sr1][sc1] = xb;
            }
            __syncthreads();
        }
    }

#pragma unroll
    for (int cs = 0; cs < 4; ++cs) {
#pragma unroll
        for (int n = 0; n < 8; ++n) {
            const int col = (cs << 7) + (n << 4) + lr;
            const float bias = pb[col];
#pragma unroll
            for (int r = 0; r < 4; ++r)
                io[(size_t)(m0 + (wv << 4) + (lk << 2) + r) * 512 + col] =
                    acc[(cs << 3) + n][r] + bias;
        }
    }
}

// ===========================================================================
// fp32 fallback path (round-8 kernels) — used if ws_size < 3 MiB.
// ===========================================================================
__device__ __forceinline__ void stage49x32(const float* src, float* dst, int t) {
#pragma unroll
    for (int it = 0; it < 2; ++it) {
        const int o = t + (it << 8);
        if (o < 392) {
            const int wb = o & ~63;
            cp16_async(src + (size_t)(o >> 3) * 512 + ((o & 7) << 2),
                       dst + (wb << 2));
        }
    }
}

#define FMA4(accv, f, w0, w1, w2, w3)                                          \
  accv.x = fmaf(f.x, w0.x, accv.x); accv.x = fmaf(f.y, w1.x, accv.x);          \
  accv.x = fmaf(f.z, w2.x, accv.x); accv.x = fmaf(f.w, w3.x, accv.x);          \
  accv.y = fmaf(f.x, w0.y, accv.y); accv.y = fmaf(f.y, w1.y, accv.y);          \
  accv.y = fmaf(f.z, w2.y, accv.y); accv.y = fmaf(f.w, w3.y, accv.y);          \
  accv.z = fmaf(f.x, w0.z, accv.z); accv.z = fmaf(f.y, w1.z, accv.z);          \
  accv.z = fmaf(f.z, w2.z, accv.z); accv.z = fmaf(f.w, w3.z, accv.z);          \
  accv.w = fmaf(f.x, w0.w, accv.w); accv.w = fmaf(f.y, w1.w, accv.w);          \
  accv.w = fmaf(f.z, w2.w, accv.w); accv.w = fmaf(f.w, w3.w, accv.w);

__global__ __launch_bounds__(256, 3) void attn2_fp32(
    const float* __restrict__ inp, const float* __restrict__ qg,
    const float* __restrict__ W, const float* __restrict__ b,
    const float* __restrict__ bt, float* __restrict__ out) {
    __shared__ float kv_s[56][132];
    __shared__ float S_s[49][50];
    __shared__ float inp_s[2][56][32];
    const int win = blockIdx.x, hg = blockIdx.y, t = threadIdx.x;
    const int c4 = t & 31, rg2 = t >> 5, wv = t >> 6, j = t & 63;
    const int colbase = (c4 < 16) ? (hg * 64 + (c4 << 2))
                                  : (512 + hg * 64 + ((c4 - 16) << 2));
    const float* ip = inp + (size_t)win * 49 * 512;
    float4 acc[7];
#pragma unroll
    for (int rr = 0; rr < 7; ++rr) acc[rr] = make_float4(0.f, 0.f, 0.f, 0.f);
    const float4 bias4 = *(const float4*)(b + colbase);
    stage49x32(ip, &inp_s[0][0][0], t);
    __syncthreads();
    for (int kc = 0; kc < 512; kc += 32) {
        const int cur = (kc >> 5) & 1;
        if (kc + 32 < 512) stage49x32(ip + kc + 32, &inp_s[cur ^ 1][0][0], t);
        const float* Wp = W + ((size_t)kc << 10) + colbase;
#pragma unroll
        for (int k4 = 0; k4 < 8; ++k4) {
            const float* wr = Wp + ((size_t)(k4 << 2) << 10);
            float4 w0 = *(const float4*)(wr);
            float4 w1 = *(const float4*)(wr + 1024);
            float4 w2 = *(const float4*)(wr + 2048);
            float4 w3 = *(const float4*)(wr + 3072);
#pragma unroll
            for (int rr = 0; rr < 7; ++rr) {
                float4 f = *(const float4*)&inp_s[cur][rg2 + (rr << 3)][k4 << 2];
                FMA4(acc[rr], f, w0, w1, w2, w3)
            }
        }
        __syncthreads();
    }
#pragma unroll
    for (int rr = 0; rr < 7; ++rr) {
        const int r = rg2 + (rr << 3);
        float4 res = make_float4(acc[rr].x + bias4.x, acc[rr].y + bias4.y,
                                 acc[rr].z + bias4.z, acc[rr].w + bias4.w);
        *(float4*)&kv_s[r][c4 << 2] = res;
    }
    const float* qwin = qg + (size_t)(win >> 4) * 49 * 512 + (hg << 6);
    stage49x32(qwin, &inp_s[0][0][0], t);
    __syncthreads();
    const int jj = (j < 49) ? j : 48;
    const int jh = jj / 7, jw = jj - jh * 7;
    const int c_j = jh * 13 + jw;
    for (int hh = 0; hh < 2; ++hh) {
        const int H = (hg << 1) + hh;
        const int qb = hh;
        if (hh == 0) stage49x32(qwin + 32, &inp_s[1][0][0], t);
        float4 kreg[8];
#pragma unroll
        for (int d4 = 0; d4 < 8; ++d4)
            kreg[d4] = *(const float4*)&kv_s[jj][(hh << 5) + (d4 << 2)];
        for (int i = wv; i < 49; i += 4) {
            const int ih = i / 7, iw = i - ih * 7;
            const int r_i = ih * 13 + iw + 84;
            float s = 0.f;
#pragma unroll
            for (int d4 = 0; d4 < 8; ++d4) {
                float4 qv = *(const float4*)&inp_s[qb][i][d4 << 2];
                s = fmaf(qv.x, kreg[d4].x, s); s = fmaf(qv.y, kreg[d4].y, s);
                s = fmaf(qv.z, kreg[d4].z, s); s = fmaf(qv.w, kreg[d4].w, s);
            }
            s = s * 0.17677669529663687f + bt[(r_i - c_j) * 16 + H];
            if (j >= 49) s = -1e30f;
            float mx = s;
#pragma unroll
            for (int m = 32; m; m >>= 1) mx = fmaxf(mx, __shfl_xor(mx, m));
            float e = __expf(s - mx);
            float sum = e;
#pragma unroll
            for (int m = 32; m; m >>= 1) sum += __shfl_xor(sum, m);
            float p = e * (1.f / sum);
            if (j < 49) S_s[i][j] = p;
        }
        __syncthreads();
        for (int o = t; o < 392; o += 256) {
            int i = o >> 3, dd = (o & 7) << 2;
            float4 a4 = make_float4(0.f, 0.f, 0.f, 0.f);
#pragma unroll 7
            for (int jq = 0; jq < 49; ++jq) {
                float p = S_s[i][jq];
                float4 vf = *(const float4*)&kv_s[jq][64 + (hh << 5) + dd];
                a4.x = fmaf(p, vf.x, a4.x); a4.y = fmaf(p, vf.y, a4.y);
                a4.z = fmaf(p, vf.z, a4.z); a4.w = fmaf(p, vf.w, a4.w);
            }
            *(float4*)(out + ((size_t)win * 49 + i) * 512 + (H << 5) + dd) = a4;
        }
        __syncthreads();
    }
}

__global__ __launch_bounds__(256, 4) void proj16_fp32(
    const float* __restrict__ pw, const float* __restrict__ pb,
    float* __restrict__ io) {
    __shared__ float X_s[16][512];
    const int m0 = blockIdx.x << 4;
    const int t = threadIdx.x;
    const int c4 = (t & 127) << 2;
    const int rg2 = t >> 7;
    const float* xsrc = io + (size_t)m0 * 512;
#pragma unroll
    for (int it = 0; it < 8; ++it) {
        const int o = t + (it << 8);
        const int wb = o & ~63;
        cp16_async(xsrc + ((size_t)o << 2), &X_s[0][0] + (wb << 2));
    }
    __syncthreads();
    const float4 bias = *(const float4*)(pb + c4);
    float4 acc[8];
#pragma unroll
    for (int r = 0; r < 8; ++r) acc[r] = bias;
    const float* wp = pw + c4;
    float4 w0 = *(const float4*)(wp);
    float4 w1 = *(const float4*)(wp + 512);
    float4 w2 = *(const float4*)(wp + 1024);
    float4 w3 = *(const float4*)(wp + 1536);
    for (int k4 = 0; k4 < 127; ++k4) {
        const float* wn2 = wp + (((size_t)k4 + 1) << 11);
        const float4 n0 = *(const float4*)(wn2);
        const float4 n1 = *(const float4*)(wn2 + 512);
        const float4 n2 = *(const float4*)(wn2 + 1024);
        const float4 n3 = *(const float4*)(wn2 + 1536);
#pragma unroll
        for (int r = 0; r < 8; ++r) {
            const float4 f = *(const float4*)&X_s[(rg2 << 3) + r][k4 << 2];
            FMA4(acc[r], f, w0, w1, w2, w3)
        }
        w0 = n0; w1 = n1; w2 = n2; w3 = n3;
    }
#pragma unroll
    for (int r = 0; r < 8; ++r) {
        const float4 f = *(const float4*)&X_s[(rg2 << 3) + r][127 << 2];
        FMA4(acc[r], f, w0, w1, w2, w3)
    }
#pragma unroll
    for (int r = 0; r < 8; ++r)
        *(float4*)(io + ((size_t)(m0 + (rg2 << 3) + r)) * 512 + c4) = acc[r];
}

// ---------------------------------------------------------------------------
extern "C" void kernel_launch(void* const* d_in, const int* in_sizes, int n_in,
                              void* d_out, int out_size, void* d_ws, size_t ws_size,
                              hipStream_t stream) {
    const float* inputs = (const float*)d_in[0];   // [1024*49, 512]
    const float* qg     = (const float*)d_in[1];   // [64*49, 512]
    const float* qkv_w  = (const float*)d_in[2];   // [512, 1024]
    const float* qkv_b  = (const float*)d_in[3];   // [1024]
    const float* btab   = (const float*)d_in[4];   // [169, 16]
    const float* proj_w = (const float*)d_in[5];   // [512, 512]
    const float* proj_b = (const float*)d_in[6];   // [512]
    float* out = (float*)d_out;                    // [1024*49, 512]

    const size_t WS_NEED = 1572864ull * sizeof(unsigned short);  // 3 MiB
    if (d_ws != nullptr && ws_size >= WS_NEED) {
        u16* wt = (u16*)d_ws;
        prep_wt<<<3072, 256, 0, stream>>>(qkv_w, proj_w, wt);
        attn2_mfma<<<dim3(1024, 8), 256, 0, stream>>>(inputs, qg, wt, qkv_b, btab, out);
        proj_mfma<<<784, 256, 0, stream>>>(wt, proj_b, out);
    } else {
        attn2_fp32<<<dim3(1024, 8), 256, 0, stream>>>(inputs, qg, qkv_w, qkv_b, btab, out);
        proj16_fp32<<<50176 / 16, 256, 0, stream>>>(proj_w, proj_b, out);
    }
}